// Round 7
// baseline (425.070 us; speedup 1.0000x reference)
//
#include <hip/hip_runtime.h>
#include <hip/hip_bf16.h>
#include <cstdint>

#define NS 100000
#define NW 5000
#define NPS 2000
#define DI 128
#define DO 64
#define NSTRIPS (NS/16)   // 6250
#define NFLAT (4*NS + NW + NPS)   // 407000 flattened dst space (intra interleaved n*4+t)
#define NWPAD 5008   // wh rows padded to strip multiple
// Density-aware buckets: intra 4096 slots (4 edges/slot avg -> 16.4K),
// wh 256 slots (40/slot -> 10.2K), sup 128 slots (100/slot -> 12.8K).
#define NBUK 134     // 98 intra + 20 wh + 16 sup
#define BCAP 20480   // >25 sigma above worst bucket mean
#define CHUNK 4096   // edges per bin-role workgroup (LDS-staged)

// k_front role block ranges (bin role count is runtime: nbin)
#define B_CONV 512    // persistent grid-stride convert role
#define B_PACK 304    // 77824/256
#define B_SWH  157
#define B_SSUP 63

typedef unsigned short bfu;
typedef __attribute__((ext_vector_type(8))) short s8v;
typedef __attribute__((ext_vector_type(4))) float f4v;

__device__ inline bfu f2bf(float f) {
  uint32_t u = __float_as_uint(f);
  u = (u + 0x7FFFu + ((u >> 16) & 1u)) >> 16;
  return (bfu)u;
}
__device__ inline float bf2f(bfu u) {
  return __uint_as_float((uint32_t)u << 16);
}

// ================= k_front: fused bin + convert + pack + scores =================
struct ESeg { const int* ei[6]; int E[6]; int Ecum[7]; };

__device__ inline void buk_of(int t, int d, int& b, int& loc) {
  if (t < 4)       { int f = d * 4 + t; b = f >> 12;        loc = f & 4095; }
  else if (t == 4) { b = 98 + (d >> 8);                     loc = d & 255; }
  else             { b = 118 + (d >> 7);                    loc = d & 127; }
}

struct PackA {
  const float* W[6]; const float* a[6];
  const float* resW; const float* projW;
  bfu* Bp; bfu* Rp; bfu* Pp;
};

struct K1Args {
  // bin
  ESeg S; int* gCur; uint32_t* binned; int ETOT; int nbin;
  // convert
  const float* x0; bfu* o0; int n0;
  const float* x1; bfu* o1; int n1;
  const float* x2; bfu* o2; int n2;
  // pack
  PackA P;
  // scores
  const float* xwh; const float* xsup; float* sd_wh; float* sd_sup;
};

// --- bin role: LDS-staged bucket-major grouping, coalesced burst flush ---
__device__ void bin_body(const K1Args& A, int bid) {
  __shared__ uint32_t stage[CHUNK];        // 16 KB
  __shared__ unsigned char bstage[CHUNK];  // 4 KB
  __shared__ int cnt[NBUK];
  __shared__ int lstart[NBUK];
  __shared__ int cur[NBUK];
  __shared__ int gbase[NBUK];
  __shared__ int wq[4];
  const ESeg& S = A.S;
  int tid = threadIdx.x;
  int lane = tid & 63, wid = tid >> 6;
  int ebase = bid * CHUNK;
  if (tid < NBUK) cnt[tid] = 0;
  __syncthreads();
  // pass 1: count per bucket
  #pragma unroll
  for (int i = 0; i < CHUNK / 256; ++i) {
    int g = ebase + i * 256 + tid;
    if (g < A.ETOT) {
      int t = 0;
      #pragma unroll
      for (int k = 0; k < 5; ++k) t += (g >= S.Ecum[k + 1]);
      int e = g - S.Ecum[t];
      int d = S.ei[t][S.E[t] + e];
      int b, loc; buk_of(t, d, b, loc);
      atomicAdd(&cnt[b], 1);
    }
  }
  __syncthreads();
  // exclusive scan over NBUK buckets
  int c = (tid < NBUK) ? cnt[tid] : 0;
  int inc = c;
  #pragma unroll
  for (int d = 1; d < 64; d <<= 1) { int t = __shfl_up(inc, d); if (lane >= d) inc += t; }
  if (lane == 63) wq[wid] = inc;
  __syncthreads();
  int wp = 0;
  for (int k = 0; k < wid; ++k) wp += wq[k];
  int excl = inc - c + wp;
  if (tid < NBUK) {
    lstart[tid] = excl;
    cur[tid] = excl;
    gbase[tid] = atomicAdd(&A.gCur[tid], c);
  }
  __syncthreads();
  // pass 2: scatter edges into LDS, bucket-major
  #pragma unroll
  for (int i = 0; i < CHUNK / 256; ++i) {
    int g = ebase + i * 256 + tid;
    if (g < A.ETOT) {
      int t = 0;
      #pragma unroll
      for (int k = 0; k < 5; ++k) t += (g >= S.Ecum[k + 1]);
      int e = g - S.Ecum[t];
      int sv = S.ei[t][e];
      int d  = S.ei[t][S.E[t] + e];
      int b, loc; buk_of(t, d, b, loc);
      int p = atomicAdd(&cur[b], 1);
      stage[p] = ((uint32_t)loc << 17) | (uint32_t)sv;
      bstage[p] = (unsigned char)b;
    }
  }
  __syncthreads();
  // flush: linear over LDS -> coalesced bursts per bucket run
  int tot = min(CHUNK, A.ETOT - ebase);
  for (int i = tid; i < tot; i += 256) {
    int b = bstage[i];
    int pos = gbase[b] + (i - lstart[b]);
    if (pos < BCAP)   // capacity guard (statistically never hit)
      A.binned[(size_t)b * BCAP + pos] = stage[i];
  }
}

// --- convert role: persistent grid-stride (512 blocks), 1 elem/step ---
__device__ void convert_body(const K1Args& A, int bid) {
  int ntot = A.n0 + A.n1 + A.n2;
  for (int t = bid * 256 + threadIdx.x; t < ntot; t += B_CONV * 256) {
    const float* x; bfu* o; int i;
    if (t < A.n0) { x = A.x0; o = A.o0; i = t; }
    else if (t < A.n0 + A.n1) { x = A.x1; o = A.o1; i = t - A.n0; }
    else { x = A.x2; o = A.o2; i = t - A.n0 - A.n1; }
    const float4* p = (const float4*)x + (size_t)i * 2;
    float4 a = p[0], b = p[1];
    uint4 v;
    v.x = (uint32_t)f2bf(a.x) | ((uint32_t)f2bf(a.y) << 16);
    v.y = (uint32_t)f2bf(a.z) | ((uint32_t)f2bf(a.w) << 16);
    v.z = (uint32_t)f2bf(b.x) | ((uint32_t)f2bf(b.y) << 16);
    v.w = (uint32_t)f2bf(b.z) | ((uint32_t)f2bf(b.w) << 16);
    ((uint4*)o)[i] = v;
  }
}

// --- pack role ---
__device__ void pack_body(const PackA& P, int bid) {
  int t = bid * 256 + threadIdx.x;
  if (t < 61440) {
    int ty = t / 10240, rem = t % 10240;
    int r = rem / 128, k = rem % 128;
    const float* W = P.W[ty]; const float* a = P.a[ty];
    float v = 0.f;
    if (r < 64) v = W[k * 64 + r];
    else if (r < 72) {
      int h = (r - 64) & 3;
      const float* av = (r < 68) ? a : (a + 16);
      #pragma unroll
      for (int m = 0; m < 16; ++m) v += W[k * 64 + h * 16 + m] * av[m];
    }
    P.Bp[ty * 10240 + rem] = f2bf(v);
  } else if (t < 69632) {
    int i = t - 61440; int j = i / 128, k = i % 128;
    P.Rp[i] = f2bf(P.resW[k * 64 + j]);
  } else if (t < 77824) {
    int i = t - 69632; int j = i / 128, k = i % 128;
    P.Pp[i] = f2bf(P.projW[k * 64 + j]);
  }
}

// --- scores role: wv recomputed inline (same m-order as pack -> same FP result) ---
__device__ void scores_body(const float* __restrict__ x, const float* __restrict__ W,
                            const float* __restrict__ a, float* __restrict__ sdst,
                            int N, int bid, int nblk) {
  int tid = threadIdx.x;
  int lane = tid & 63;
  float wa[4] = {0.f, 0.f, 0.f, 0.f}, wb[4] = {0.f, 0.f, 0.f, 0.f};
  for (int m = 0; m < 16; ++m) {
    float av = a[16 + m];
    #pragma unroll
    for (int h = 0; h < 4; ++h) {
      wa[h] += W[lane * 64 + h * 16 + m] * av;
      wb[h] += W[(64 + lane) * 64 + h * 16 + m] * av;
    }
  }
  int w  = (bid * 256 + tid) >> 6;
  int nw = (nblk * 256) >> 6;
  for (int n = w; n < N; n += nw) {
    float xa = x[(size_t)n * 128 + lane], xc = x[(size_t)n * 128 + 64 + lane];
    float4 r;
    r.x = xa * wa[0] + xc * wb[0]; r.y = xa * wa[1] + xc * wb[1];
    r.z = xa * wa[2] + xc * wb[2]; r.w = xa * wa[3] + xc * wb[3];
    #pragma unroll
    for (int m = 1; m < 64; m <<= 1) {
      r.x += __shfl_xor(r.x, m); r.y += __shfl_xor(r.y, m);
      r.z += __shfl_xor(r.z, m); r.w += __shfl_xor(r.w, m);
    }
    if (lane == 0) ((float4*)sdst)[n] = r;
  }
}

__global__ __launch_bounds__(256) void k_front(K1Args A) {
  int bid = blockIdx.x;
  if (bid < A.nbin) { bin_body(A, bid); return; }
  bid -= A.nbin;
  if (bid < B_CONV) { convert_body(A, bid); return; }
  bid -= B_CONV;
  if (bid < B_PACK) { pack_body(A.P, bid); return; }
  bid -= B_PACK;
  if (bid < B_SWH) { scores_body(A.xwh, A.P.W[4], A.P.a[4], A.sd_wh, NW, bid, B_SWH); return; }
  bid -= B_SWH;
  scores_body(A.xsup, A.P.W[5], A.P.a[5], A.sd_sup, NPS, bid, B_SSUP);
}

// ================= k_mid: fused CSR pass-B + node GEMMs (independent roles) =================
struct MidArgs {
  // csr
  const int* gCur; const uint32_t* binned; int* offs; int* ssorted;
  // gemm
  const bfu* xb; const bfu* Bp;
  bfu* hbAll; float* ssAll; float* sdAll; int nstrips;
};

// csr role, 256 threads: parallel bucket-base scan + 16-elem/thread hist scan
__device__ void csr_body(const MidArgs& M, int b) {
  __shared__ int hist[4096];
  __shared__ int wq[4];
  __shared__ int wsc[4];
  __shared__ int bbase_s, cnt_s;
  int tid = threadIdx.x;
  int lane = tid & 63, wid = tid >> 6;
  // bucket base/count via 256-wide scan over clamped cursors
  int cthis = (tid < NBUK) ? min(M.gCur[tid], BCAP) : 0;
  int incx = cthis;
  #pragma unroll
  for (int d = 1; d < 64; d <<= 1) { int t = __shfl_up(incx, d); if (lane >= d) incx += t; }
  if (lane == 63) wq[wid] = incx;
  #pragma unroll
  for (int k = 0; k < 16; ++k) hist[tid * 16 + k] = 0;
  __syncthreads();
  int wp = 0;
  for (int k = 0; k < wid; ++k) wp += wq[k];
  if (tid == b) { int inclusive = incx + wp; bbase_s = inclusive - cthis; cnt_s = cthis; }
  __syncthreads();
  int cnt = cnt_s, bbase = bbase_s;
  const uint32_t* bk = M.binned + (size_t)b * BCAP;
  for (int i = tid; i < cnt; i += 256)
    atomicAdd(&hist[bk[i] >> 17], 1);
  __syncthreads();
  // block exclusive scan over 4096 (16 slots/thread)
  int t16 = tid * 16;
  int v[16], tsum = 0;
  #pragma unroll
  for (int k = 0; k < 16; ++k) { v[k] = hist[t16 + k]; tsum += v[k]; }
  int inc = tsum;
  #pragma unroll
  for (int d = 1; d < 64; d <<= 1) { int t = __shfl_up(inc, d); if (lane >= d) inc += t; }
  if (lane == 63) wsc[wid] = inc;
  __syncthreads();
  int wpre = 0;
  for (int k = 0; k < wid; ++k) wpre += wsc[k];
  int run = inc - tsum + wpre;
  #pragma unroll
  for (int k = 0; k < 16; ++k) { hist[t16 + k] = run; run += v[k]; }
  __syncthreads();
  // coalesced offs write for this bucket's slot range
  int sbase, nslots;
  if (b < 98)        { sbase = b << 12;                nslots = min(4096, 4 * NS - sbase); }
  else if (b < 118)  { int lb = (b - 98) << 8;  sbase = 4 * NS + lb;      nslots = min(256, NW - lb); }
  else               { int lb = (b - 118) << 7; sbase = 4 * NS + NW + lb; nslots = min(128, NPS - lb); }
  for (int i = tid; i < nslots; i += 256) M.offs[sbase + i] = bbase + hist[i];
  if (b == NBUK - 1 && tid == 0) M.offs[NFLAT] = bbase + cnt;
  __syncthreads();
  // scatter (hist doubles as cursor)
  for (int i = tid; i < cnt; i += 256) {
    uint32_t vv = bk[i];
    int p = atomicAdd(&hist[vv >> 17], 1);
    M.ssorted[bbase + p] = (int)(vv & 0x1FFFFu);
  }
}

// gemm role: B-frags loaded per-kq from (L2-hot) Bp -> VGPR diet, higher occupancy
__device__ void gemm_body(const MidArgs& G, int bloc) {
  int p = bloc >> 9;        // 0..2 : type pair (2p, 2p+1)
  int bsub = bloc & 511;
  const bfu* Bp0 = G.Bp + (size_t)(2 * p) * 10240;
  const bfu* Bp1 = G.Bp + (size_t)(2 * p + 1) * 10240;
  bfu* hb0 = G.hbAll + (size_t)(2 * p) * NS * 64;
  bfu* hb1 = G.hbAll + (size_t)(2 * p + 1) * NS * 64;
  float* ss0 = G.ssAll + (size_t)(2 * p) * NS * 4;
  float* ss1 = G.ssAll + (size_t)(2 * p + 1) * NS * 4;
  float* sd0 = G.sdAll + (size_t)(2 * p) * NS * 4;
  float* sd1 = G.sdAll + (size_t)(2 * p + 1) * NS * 4;
  int lane = threadIdx.x & 63;
  int l15 = lane & 15, q = lane >> 4;
  int w  = (int)((bsub * 256 + threadIdx.x) >> 6);
  int nw = (512 * 256) >> 6;
  for (int s = w; s < G.nstrips; s += nw) {
    int mb = s * 16;
    f4v acc[10];
    #pragma unroll
    for (int u = 0; u < 10; ++u) acc[u] = (f4v){0.f, 0.f, 0.f, 0.f};
    const bfu* ar = G.xb + (size_t)(mb + l15) * 128 + q * 8;
    #pragma unroll
    for (int kq = 0; kq < 4; ++kq) {
      s8v af = *(const s8v*)(ar + kq * 32);
      s8v bfr[10];
      #pragma unroll
      for (int nt = 0; nt < 5; ++nt) {
        bfr[nt]     = *(const s8v*)(Bp0 + (size_t)(nt * 16 + l15) * 128 + kq * 32 + q * 8);
        bfr[5 + nt] = *(const s8v*)(Bp1 + (size_t)(nt * 16 + l15) * 128 + kq * 32 + q * 8);
      }
      #pragma unroll
      for (int u = 0; u < 10; ++u)
        acc[u] = __builtin_amdgcn_mfma_f32_16x16x32_bf16(af, bfr[u], acc[u], 0, 0, 0);
    }
    #pragma unroll
    for (int u = 0; u < 10; ++u) {
      int nt = (u < 5) ? u : u - 5;
      bfu* hb = (u < 5) ? hb0 : hb1;
      float* ssrc = (u < 5) ? ss0 : ss1;
      float* sdst = (u < 5) ? sd0 : sd1;
      int c = nt * 16 + l15;
      #pragma unroll
      for (int r = 0; r < 4; ++r) {
        int node = mb + q * 4 + r;
        float v = acc[u][r];
        if (c < 64)      hb[(size_t)node * 64 + c] = f2bf(v);
        else if (c < 68) ssrc[(size_t)node * 4 + (c - 64)] = v;
        else if (c < 72) sdst[(size_t)node * 4 + (c - 68)] = v;
      }
    }
  }
}

__global__ __launch_bounds__(256, 3) void k_mid(MidArgs M) {
  int bid = blockIdx.x;
  if (bid < NBUK) { csr_body(M, bid); return; }
  gemm_body(M, bid - NBUK);
}

// ================= fused softmax-aggregate (v3 math, 2048-block persistent grid) =================
struct AggArgs {
  const int* offs; const int* srcs;
  const bfu* hbAll;     // [6][NS][64]
  const float* ssAll;   // [6][NS][4]
  const float* sdAll;   // [6][NS][4] (types 4,5 unused)
  const float* sd_wh; const float* sd_sup;
  bfu* osku; bfu* owh; bfu* osup;
};

__global__ __launch_bounds__(256) void k_megaagg(AggArgs A) {
  int lane = threadIdx.x & 63;
  int q = lane >> 4, m = lane & 15, h = m >> 2;
  int hh = m & 3;          // head this lane SCORES
  int i0 = m >> 2;         // edge slot (0..3) this lane scores
  int qsh = q << 4;
  int sl0 = qsh + h;       // base of wgt-broadcast source lane: + 4*(i&3)
  int w  = (int)((blockIdx.x * 256 + threadIdx.x) >> 6);
  int nw = (int)((gridDim.x * 256) >> 6);
  for (int n = w; n < NS + NW + NPS; n += nw) {
    if (n < NS) {
      const int* ob = A.offs + (size_t)n * 4;
      int4 o = *(const int4*)ob;
      int o4 = ob[4];
      int sb = (q == 0) ? o.x : (q == 1) ? o.y : (q == 2) ? o.z : o.w;
      int se = (q == 0) ? o.y : (q == 1) ? o.z : (q == 2) ? o.w : o4;
      int len = se - sb;
      int maxlen = max(max(o.y - o.x, o.z - o.y), max(o.w - o.z, o4 - o.w));
      float sdq = A.sdAll[((size_t)q * NS + n) * 4 + hh];
      uint32_t tbase = (uint32_t)q * (uint32_t)NS;
      float den = 0.f, a0 = 0.f, a1 = 0.f, a2 = 0.f, a3 = 0.f;
      for (int j0 = 0; j0 < maxlen; j0 += 16) {
        int ei = j0 + m;
        int sidx = (ei < len) ? A.srcs[sb + ei] : 0;
        int gmax = min(16, maxlen - j0);
        for (int jj = 0; jj < gmax; jj += 8) {
          // phase 1: score edges (jj+i0) and (jj+4+i0) for head hh
          int sA = __shfl(sidx, qsh + jj + i0);
          int sB = __shfl(sidx, qsh + jj + 4 + i0);
          float scA = A.ssAll[(tbase + (uint32_t)sA) * 4u + (uint32_t)hh];
          float scB = A.ssAll[(tbase + (uint32_t)sB) * 4u + (uint32_t)hh];
          float eA = scA + sdq, eB = scB + sdq;
          eA = eA > 0.f ? eA : (__expf(eA) - 1.f);
          eB = eB > 0.f ? eB : (__expf(eB) - 1.f);
          float wA = (j0 + jj + i0)     < len ? __expf(eA) : 0.f;
          float wB = (j0 + jj + 4 + i0) < len ? __expf(eB) : 0.f;
          // phase 2: gather h-rows + broadcast weights
          uint2 hv[8]; float wg[8];
          #pragma unroll
          for (int i = 0; i < 8; ++i) {
            int s = __shfl(sidx, qsh + jj + i);
            uint32_t nb = tbase + (uint32_t)s;
            hv[i] = *(const uint2*)(A.hbAll + nb * 64u + (uint32_t)(m * 4));
            wg[i] = __shfl((i & 4) ? wB : wA, sl0 + ((i & 3) << 2));
          }
          #pragma unroll
          for (int i = 0; i < 8; ++i) {
            float wgt = wg[i];
            den += wgt;
            a0 = fmaf(__uint_as_float(hv[i].x << 16), wgt, a0);
            a1 = fmaf(__uint_as_float(hv[i].x & 0xffff0000u), wgt, a1);
            a2 = fmaf(__uint_as_float(hv[i].y << 16), wgt, a2);
            a3 = fmaf(__uint_as_float(hv[i].y & 0xffff0000u), wgt, a3);
          }
        }
      }
      float inv = __builtin_amdgcn_rcpf(den + 1e-12f);
      float r0 = a0 * inv, r1 = a1 * inv, r2 = a2 * inv, r3 = a3 * inv;
      r0 += __shfl_xor(r0, 16); r0 += __shfl_xor(r0, 32);
      r1 += __shfl_xor(r1, 16); r1 += __shfl_xor(r1, 32);
      r2 += __shfl_xor(r2, 16); r2 += __shfl_xor(r2, 32);
      r3 += __shfl_xor(r3, 16); r3 += __shfl_xor(r3, 32);
      if (q == 0) {
        uint2 pk;
        pk.x = (uint32_t)f2bf(r0) | ((uint32_t)f2bf(r1) << 16);
        pk.y = (uint32_t)f2bf(r2) | ((uint32_t)f2bf(r3) << 16);
        *(uint2*)(A.osku + (size_t)n * 64 + m * 4) = pk;
      }
    } else {
      int tt, nl; const float* sd; bfu* op;
      int fi;
      if (n < NS + NW) { tt = 4; nl = n - NS; fi = 4 * NS + nl; sd = A.sd_wh; op = A.owh + (size_t)nl * 64; }
      else { tt = 5; nl = n - NS - NW; fi = 4 * NS + NW + nl; sd = A.sd_sup; op = A.osup + (size_t)nl * 64; }
      int beg = A.offs[fi], end = A.offs[fi + 1];
      uint32_t tbase = (uint32_t)tt * (uint32_t)NS;
      float sdq = sd[(size_t)nl * 4 + hh];
      float den = 0.f, a0 = 0.f, a1 = 0.f, a2 = 0.f, a3 = 0.f;
      for (int cb = beg; cb < end; cb += 64) {
        int rem = min(64, end - cb);
        int sidx = (lane < rem) ? A.srcs[cb + lane] : 0;
        for (int jb = 0; jb < rem; jb += 32) {
          // phase 1: score edges jb+4*i0+q and jb+4*(i0+4)+q for head hh
          int eA = jb + 4 * i0 + q;
          int sA = __shfl(sidx, eA);
          int sB = __shfl(sidx, eA + 16);
          float scA = A.ssAll[(tbase + (uint32_t)sA) * 4u + (uint32_t)hh];
          float scB = A.ssAll[(tbase + (uint32_t)sB) * 4u + (uint32_t)hh];
          float fA = scA + sdq, fB = scB + sdq;
          fA = fA > 0.f ? fA : (__expf(fA) - 1.f);
          fB = fB > 0.f ? fB : (__expf(fB) - 1.f);
          float wA = (eA)      < rem ? __expf(fA) : 0.f;
          float wB = (eA + 16) < rem ? __expf(fB) : 0.f;
          uint2 hv[8]; float wg[8];
          #pragma unroll
          for (int i = 0; i < 8; ++i) {
            int s = __shfl(sidx, jb + 4 * i + q);
            uint32_t nb = tbase + (uint32_t)s;
            hv[i] = *(const uint2*)(A.hbAll + nb * 64u + (uint32_t)(m * 4));
            wg[i] = __shfl((i & 4) ? wB : wA, sl0 + ((i & 3) << 2));
          }
          #pragma unroll
          for (int i = 0; i < 8; ++i) {
            float wgt = wg[i];
            den += wgt;
            a0 = fmaf(__uint_as_float(hv[i].x << 16), wgt, a0);
            a1 = fmaf(__uint_as_float(hv[i].x & 0xffff0000u), wgt, a1);
            a2 = fmaf(__uint_as_float(hv[i].y << 16), wgt, a2);
            a3 = fmaf(__uint_as_float(hv[i].y & 0xffff0000u), wgt, a3);
          }
        }
      }
      den += __shfl_xor(den, 16); den += __shfl_xor(den, 32);
      a0 += __shfl_xor(a0, 16); a0 += __shfl_xor(a0, 32);
      a1 += __shfl_xor(a1, 16); a1 += __shfl_xor(a1, 32);
      a2 += __shfl_xor(a2, 16); a2 += __shfl_xor(a2, 32);
      a3 += __shfl_xor(a3, 16); a3 += __shfl_xor(a3, 32);
      float inv = __builtin_amdgcn_rcpf(den + 1e-12f);
      if (q == 0) {
        uint2 pk;
        pk.x = (uint32_t)f2bf(a0 * inv) | ((uint32_t)f2bf(a1 * inv) << 16);
        pk.y = (uint32_t)f2bf(a2 * inv) | ((uint32_t)f2bf(a3 * inv) << 16);
        *(uint2*)(op + m * 4) = pk;
      }
    }
  }
}

// ================= MFMA finish: all 3 node sets in ONE dispatch (4 strips/wave) =================
struct FinArgs {
  const bfu* agg0; const bfu* agg1; const bfu* agg2;
  const bfu* x0; const bfu* x1; const bfu* x2;
  float* out0; float* out1; float* out2;
  const bfu* Pp; const bfu* Rp;
  const float* pb; const float* g; const float* bb;
  int bcut0, bcut1;   // role boundaries: [0,bcut0)=sku, [bcut0,bcut1)=wh, rest=sup
};

__global__ __launch_bounds__(256) void k_finish(FinArgs F) {
  int bid = blockIdx.x;
  int role = (bid >= F.bcut0) + (bid >= F.bcut1);
  int b0 = (role == 0) ? 0 : (role == 1) ? F.bcut0 : F.bcut1;
  int nb = (role == 0) ? F.bcut0 : (role == 1) ? (F.bcut1 - F.bcut0) : ((int)gridDim.x - F.bcut1);
  int bloc = bid - b0;
  const bfu* aggb = (role == 0) ? F.agg0 : (role == 1) ? F.agg1 : F.agg2;
  const bfu* xbf  = (role == 0) ? F.x0 : (role == 1) ? F.x1 : F.x2;
  float* outp     = (role == 0) ? F.out0 : (role == 1) ? F.out1 : F.out2;
  int koff    = (role == 0) ? 0 : 64;
  int N       = (role == 0) ? NS : (role == 1) ? NW : NPS;
  int nstrips = (role == 0) ? NSTRIPS : (role == 1) ? (NWPAD / 16) : (NPS / 16);

  int lane = threadIdx.x & 63, l15 = lane & 15, q = lane >> 4;
  int w  = (int)((bloc * 256 + threadIdx.x) >> 6);
  int nw = nb << 2;
  s8v bP[4][2], bR[4][4];
  float pbv[4], gv[4], bv[4];
  #pragma unroll
  for (int c = 0; c < 4; ++c) {
    const bfu* pr = F.Pp + (size_t)(c * 16 + l15) * 128 + koff;
    bP[c][0] = *(const s8v*)(pr + q * 8);
    bP[c][1] = *(const s8v*)(pr + 32 + q * 8);
    const bfu* rr = F.Rp + (size_t)(c * 16 + l15) * 128;
    #pragma unroll
    for (int kq = 0; kq < 4; ++kq) bR[c][kq] = *(const s8v*)(rr + kq * 32 + q * 8);
    pbv[c] = F.pb[c * 16 + l15]; gv[c] = F.g[c * 16 + l15]; bv[c] = F.bb[c * 16 + l15];
  }
  for (int s = w; s < nstrips; s += nw) {
    int mb = s * 16;
    const bfu* ar = aggb + (size_t)(mb + l15) * 64 + q * 8;
    const bfu* xr = xbf + (size_t)(mb + l15) * 128 + q * 8;
    s8v a0 = *(const s8v*)ar, a1 = *(const s8v*)(ar + 32);
    s8v x0 = *(const s8v*)xr, x1 = *(const s8v*)(xr + 32),
        x2 = *(const s8v*)(xr + 64), x3 = *(const s8v*)(xr + 96);
    f4v acc[4];
    #pragma unroll
    for (int c = 0; c < 4; ++c) {
      acc[c] = (f4v){0.f, 0.f, 0.f, 0.f};
      acc[c] = __builtin_amdgcn_mfma_f32_16x16x32_bf16(a0, bP[c][0], acc[c], 0, 0, 0);
      acc[c] = __builtin_amdgcn_mfma_f32_16x16x32_bf16(a1, bP[c][1], acc[c], 0, 0, 0);
      acc[c] = __builtin_amdgcn_mfma_f32_16x16x32_bf16(x0, bR[c][0], acc[c], 0, 0, 0);
      acc[c] = __builtin_amdgcn_mfma_f32_16x16x32_bf16(x1, bR[c][1], acc[c], 0, 0, 0);
      acc[c] = __builtin_amdgcn_mfma_f32_16x16x32_bf16(x2, bR[c][2], acc[c], 0, 0, 0);
      acc[c] = __builtin_amdgcn_mfma_f32_16x16x32_bf16(x3, bR[c][3], acc[c], 0, 0, 0);
    }
    #pragma unroll
    for (int r = 0; r < 4; ++r) {
      int row = mb + q * 4 + r;
      float y0 = acc[0][r] + pbv[0], y1 = acc[1][r] + pbv[1];
      float y2 = acc[2][r] + pbv[2], y3 = acc[3][r] + pbv[3];
      float s1 = y0 + y1 + y2 + y3;
      s1 += __shfl_xor(s1, 1); s1 += __shfl_xor(s1, 2);
      s1 += __shfl_xor(s1, 4); s1 += __shfl_xor(s1, 8);
      float mu = s1 * 0.015625f;
      float d0 = y0 - mu, d1 = y1 - mu, d2 = y2 - mu, d3 = y3 - mu;
      float s2 = d0 * d0 + d1 * d1 + d2 * d2 + d3 * d3;
      s2 += __shfl_xor(s2, 1); s2 += __shfl_xor(s2, 2);
      s2 += __shfl_xor(s2, 4); s2 += __shfl_xor(s2, 8);
      float rs = rsqrtf(s2 * 0.015625f + 1e-5f);
      if (row < N) {
        float* orow = outp + (size_t)row * 64 + l15;
        orow[0]  = d0 * rs * gv[0] + bv[0];
        orow[16] = d1 * rs * gv[1] + bv[1];
        orow[32] = d2 * rs * gv[2] + bv[2];
        orow[48] = d3 * rs * gv[3] + bv[3];
      }
    }
  }
}

// ================= launch =================
extern "C" void kernel_launch(void* const* d_in, const int* in_sizes, int n_in,
                              void* d_out, int out_size, void* d_ws, size_t ws_size,
                              hipStream_t stream) {
  const float* x_sku = (const float*)d_in[0];
  const float* x_wh  = (const float*)d_in[1];
  const float* x_sup = (const float*)d_in[2];
  const float* Wt[6]; const float* at[6];
  for (int t = 0; t < 6; ++t) { Wt[t] = (const float*)d_in[3 + 2 * t]; at[t] = (const float*)d_in[4 + 2 * t]; }
  const float* projW = (const float*)d_in[15];
  const float* projb = (const float*)d_in[16];
  const float* lng   = (const float*)d_in[17];
  const float* lnb   = (const float*)d_in[18];
  const float* resW  = (const float*)d_in[19];
  const int* ei[6]; int Et[6];
  for (int t = 0; t < 6; ++t) { ei[t] = (const int*)d_in[20 + t]; Et[t] = in_sizes[20 + t] / 2; }
  float* out = (float*)d_out;

  int ETOT = 0;
  for (int t = 0; t < 6; ++t) ETOT += Et[t];

  char* ws = (char*)d_ws;
  size_t off = 0;
  auto alloc = [&](size_t bytes) { off = (off + 255) & ~(size_t)255; void* p = ws + off; off += bytes; return p; };

  bfu*  xb      = (bfu*)alloc((size_t)NS * DI * 2);
  bfu*  xb_wh   = (bfu*)alloc((size_t)NWPAD * DI * 2);
  bfu*  xb_sup  = (bfu*)alloc((size_t)NPS * DI * 2);
  bfu*  Bp      = (bfu*)alloc((size_t)6 * 80 * 128 * 2);
  bfu*  Rp      = (bfu*)alloc((size_t)64 * 128 * 2);
  bfu*  Pp      = (bfu*)alloc((size_t)64 * 128 * 2);
  bfu*  hbAll   = (bfu*)alloc((size_t)6 * NS * 64 * 2);
  float* ssAll  = (float*)alloc((size_t)6 * NS * 4 * 4);
  float* sdAll  = (float*)alloc((size_t)6 * NS * 4 * 4);
  float* sdst_wh  = (float*)alloc((size_t)NW * 4 * 4);
  float* sdst_sup = (float*)alloc((size_t)NPS * 4 * 4);
  // union: binned (used only before megaagg) aliases agg buffers (written by megaagg)
  size_t agg_bytes = ((size_t)NS + NWPAD + NPS) * 64 * 2;   // 13.7 MB
  size_t bin_bytes = (size_t)NBUK * BCAP * 4;               // 11.0 MB
  char* un = (char*)alloc(agg_bytes > bin_bytes ? agg_bytes : bin_bytes);
  bfu* agg_sku = (bfu*)un;
  bfu* agg_wh  = agg_sku + (size_t)NS * 64;
  bfu* agg_sup = agg_wh + (size_t)NWPAD * 64;
  uint32_t* binned = (uint32_t*)un;
  int* gCur    = (int*)alloc(256 * 4);
  int* offsb   = (int*)alloc((size_t)(NFLAT + 1) * 4);
  int* ssorted = (int*)alloc((size_t)ETOT * 4);

  // zero relative bucket cursors
  hipMemsetAsync(gCur, 0, NBUK * 4, stream);

  // ---- K1: fused bin + convert + pack + scores ----
  K1Args K;
  K.S.Ecum[0] = 0;
  for (int t = 0; t < 6; ++t) { K.S.ei[t] = ei[t]; K.S.E[t] = Et[t]; K.S.Ecum[t + 1] = K.S.Ecum[t] + Et[t]; }
  K.gCur = gCur; K.binned = binned; K.ETOT = ETOT;
  K.nbin = (ETOT + CHUNK - 1) / CHUNK;
  K.x0 = x_sku; K.o0 = xb;     K.n0 = NS * 16;
  K.x1 = x_wh;  K.o1 = xb_wh;  K.n1 = NW * 16;
  K.x2 = x_sup; K.o2 = xb_sup; K.n2 = NPS * 16;
  for (int t = 0; t < 6; ++t) { K.P.W[t] = Wt[t]; K.P.a[t] = at[t]; }
  K.P.resW = resW; K.P.projW = projW; K.P.Bp = Bp; K.P.Rp = Rp; K.P.Pp = Pp;
  K.xwh = x_wh; K.xsup = x_sup; K.sd_wh = sdst_wh; K.sd_sup = sdst_sup;
  int gfront = K.nbin + B_CONV + B_PACK + B_SWH + B_SSUP;
  k_front<<<gfront, 256, 0, stream>>>(K);

  // ---- K2: fused CSR pass-B + node GEMMs ----
  MidArgs M;
  M.gCur = gCur; M.binned = binned; M.offs = offsb; M.ssorted = ssorted;
  M.xb = xb; M.Bp = Bp; M.hbAll = hbAll; M.ssAll = ssAll; M.sdAll = sdAll; M.nstrips = NSTRIPS;
  k_mid<<<NBUK + 1536, 256, 0, stream>>>(M);

  // ---- fused aggregate (persistent grid) ----
  AggArgs A;
  A.offs = offsb; A.srcs = ssorted;
  A.hbAll = hbAll; A.ssAll = ssAll; A.sdAll = sdAll;
  A.sd_wh = sdst_wh; A.sd_sup = sdst_sup;
  A.osku = agg_sku; A.owh = agg_wh; A.osup = agg_sup;
  k_megaagg<<<2048, 256, 0, stream>>>(A);

  // ---- MFMA finish (all 3 node sets, one dispatch; ~4 strips/wave) ----
  FinArgs F;
  F.agg0 = agg_sku; F.agg1 = agg_wh; F.agg2 = agg_sup;
  F.x0 = xb; F.x1 = xb_wh; F.x2 = xb_sup;
  F.out0 = out; F.out1 = out + (size_t)NS * 64; F.out2 = out + (size_t)(NS + NW) * 64;
  F.Pp = Pp; F.Rp = Rp; F.pb = projb; F.g = lng; F.bb = lnb;
  F.bcut0 = 391; F.bcut1 = 391 + 20;
  k_finish<<<391 + 20 + 8, 256, 0, stream>>>(F);
}

// Round 8
// 375.472 us; speedup vs baseline: 1.1321x; 1.1321x over previous
//
#include <hip/hip_runtime.h>
#include <hip/hip_bf16.h>
#include <cstdint>

#define NS 100000
#define NW 5000
#define NPS 2000
#define DI 128
#define DO 64
#define NSTRIPS (NS/16)   // 6250
#define NFLAT (4*NS + NW + NPS)   // 407000 flattened dst space (intra interleaved n*4+t)
#define NWPAD 5008   // wh rows padded to strip multiple
// Density-aware buckets: intra 4096 slots (4 edges/slot avg -> 16.4K),
// wh 256 slots (40/slot -> 10.2K), sup 128 slots (100/slot -> 12.8K).
#define NBUK 134     // 98 intra + 20 wh + 16 sup
#define BCAP 20480   // >25 sigma above worst bucket mean
#define CHUNK 4096   // edges per bin-role workgroup (LDS-staged)

// k_front role block ranges (bin role count is runtime: nbin)
#define B_CONV 512    // persistent grid-stride convert role
#define B_PACK 304    // 77824/256
#define B_SWH  157
#define B_SSUP 63

typedef unsigned short bfu;
typedef __attribute__((ext_vector_type(8))) short s8v;
typedef __attribute__((ext_vector_type(4))) float f4v;

__device__ inline bfu f2bf(float f) {
  uint32_t u = __float_as_uint(f);
  u = (u + 0x7FFFu + ((u >> 16) & 1u)) >> 16;
  return (bfu)u;
}
__device__ inline float bf2f(bfu u) {
  return __uint_as_float((uint32_t)u << 16);
}

// ================= k_front: fused bin + convert + pack + scores =================
struct ESeg { const int* ei[6]; int E[6]; int Ecum[7]; };

__device__ inline void buk_of(int t, int d, int& b, int& loc) {
  if (t < 4)       { int f = d * 4 + t; b = f >> 12;        loc = f & 4095; }
  else if (t == 4) { b = 98 + (d >> 8);                     loc = d & 255; }
  else             { b = 118 + (d >> 7);                    loc = d & 127; }
}

struct PackA {
  const float* W[6]; const float* a[6];
  const float* resW; const float* projW;
  bfu* Bp; bfu* Rp; bfu* Pp;
};

struct K1Args {
  // bin
  ESeg S; int* gCur; uint32_t* binned; int ETOT; int nbin;
  // convert
  const float* x0; bfu* o0; int n0;
  const float* x1; bfu* o1; int n1;
  const float* x2; bfu* o2; int n2;
  // pack
  PackA P;
  // scores
  const float* xwh; const float* xsup; float* sd_wh; float* sd_sup;
};

// --- bin role: LDS-staged bucket-major grouping, coalesced burst flush ---
__device__ void bin_body(const K1Args& A, int bid) {
  __shared__ uint32_t stage[CHUNK];        // 16 KB
  __shared__ unsigned char bstage[CHUNK];  // 4 KB
  __shared__ int cnt[NBUK];
  __shared__ int lstart[NBUK];
  __shared__ int cur[NBUK];
  __shared__ int gbase[NBUK];
  __shared__ int wq[4];
  const ESeg& S = A.S;
  int tid = threadIdx.x;
  int lane = tid & 63, wid = tid >> 6;
  int ebase = bid * CHUNK;
  if (tid < NBUK) cnt[tid] = 0;
  __syncthreads();
  // pass 1: count per bucket
  #pragma unroll
  for (int i = 0; i < CHUNK / 256; ++i) {
    int g = ebase + i * 256 + tid;
    if (g < A.ETOT) {
      int t = 0;
      #pragma unroll
      for (int k = 0; k < 5; ++k) t += (g >= S.Ecum[k + 1]);
      int e = g - S.Ecum[t];
      int d = S.ei[t][S.E[t] + e];
      int b, loc; buk_of(t, d, b, loc);
      atomicAdd(&cnt[b], 1);
    }
  }
  __syncthreads();
  // exclusive scan over NBUK buckets
  int c = (tid < NBUK) ? cnt[tid] : 0;
  int inc = c;
  #pragma unroll
  for (int d = 1; d < 64; d <<= 1) { int t = __shfl_up(inc, d); if (lane >= d) inc += t; }
  if (lane == 63) wq[wid] = inc;
  __syncthreads();
  int wp = 0;
  for (int k = 0; k < wid; ++k) wp += wq[k];
  int excl = inc - c + wp;
  if (tid < NBUK) {
    lstart[tid] = excl;
    cur[tid] = excl;
    gbase[tid] = atomicAdd(&A.gCur[tid], c);
  }
  __syncthreads();
  // pass 2: scatter edges into LDS, bucket-major
  #pragma unroll
  for (int i = 0; i < CHUNK / 256; ++i) {
    int g = ebase + i * 256 + tid;
    if (g < A.ETOT) {
      int t = 0;
      #pragma unroll
      for (int k = 0; k < 5; ++k) t += (g >= S.Ecum[k + 1]);
      int e = g - S.Ecum[t];
      int sv = S.ei[t][e];
      int d  = S.ei[t][S.E[t] + e];
      int b, loc; buk_of(t, d, b, loc);
      int p = atomicAdd(&cur[b], 1);
      stage[p] = ((uint32_t)loc << 17) | (uint32_t)sv;
      bstage[p] = (unsigned char)b;
    }
  }
  __syncthreads();
  // flush: linear over LDS -> coalesced bursts per bucket run
  int tot = min(CHUNK, A.ETOT - ebase);
  for (int i = tid; i < tot; i += 256) {
    int b = bstage[i];
    int pos = gbase[b] + (i - lstart[b]);
    if (pos < BCAP)   // capacity guard (statistically never hit)
      A.binned[(size_t)b * BCAP + pos] = stage[i];
  }
}

// --- convert role: persistent grid-stride (512 blocks), 1 elem/step ---
__device__ void convert_body(const K1Args& A, int bid) {
  int ntot = A.n0 + A.n1 + A.n2;
  for (int t = bid * 256 + threadIdx.x; t < ntot; t += B_CONV * 256) {
    const float* x; bfu* o; int i;
    if (t < A.n0) { x = A.x0; o = A.o0; i = t; }
    else if (t < A.n0 + A.n1) { x = A.x1; o = A.o1; i = t - A.n0; }
    else { x = A.x2; o = A.o2; i = t - A.n0 - A.n1; }
    const float4* p = (const float4*)x + (size_t)i * 2;
    float4 a = p[0], b = p[1];
    uint4 v;
    v.x = (uint32_t)f2bf(a.x) | ((uint32_t)f2bf(a.y) << 16);
    v.y = (uint32_t)f2bf(a.z) | ((uint32_t)f2bf(a.w) << 16);
    v.z = (uint32_t)f2bf(b.x) | ((uint32_t)f2bf(b.y) << 16);
    v.w = (uint32_t)f2bf(b.z) | ((uint32_t)f2bf(b.w) << 16);
    ((uint4*)o)[i] = v;
  }
}

// --- pack role ---
__device__ void pack_body(const PackA& P, int bid) {
  int t = bid * 256 + threadIdx.x;
  if (t < 61440) {
    int ty = t / 10240, rem = t % 10240;
    int r = rem / 128, k = rem % 128;
    const float* W = P.W[ty]; const float* a = P.a[ty];
    float v = 0.f;
    if (r < 64) v = W[k * 64 + r];
    else if (r < 72) {
      int h = (r - 64) & 3;
      const float* av = (r < 68) ? a : (a + 16);
      #pragma unroll
      for (int m = 0; m < 16; ++m) v += W[k * 64 + h * 16 + m] * av[m];
    }
    P.Bp[ty * 10240 + rem] = f2bf(v);
  } else if (t < 69632) {
    int i = t - 61440; int j = i / 128, k = i % 128;
    P.Rp[i] = f2bf(P.resW[k * 64 + j]);
  } else if (t < 77824) {
    int i = t - 69632; int j = i / 128, k = i % 128;
    P.Pp[i] = f2bf(P.projW[k * 64 + j]);
  }
}

// --- scores role: wv recomputed inline (same m-order as pack -> same FP result) ---
__device__ void scores_body(const float* __restrict__ x, const float* __restrict__ W,
                            const float* __restrict__ a, float* __restrict__ sdst,
                            int N, int bid, int nblk) {
  int tid = threadIdx.x;
  int lane = tid & 63;
  float wa[4] = {0.f, 0.f, 0.f, 0.f}, wb[4] = {0.f, 0.f, 0.f, 0.f};
  for (int m = 0; m < 16; ++m) {
    float av = a[16 + m];
    #pragma unroll
    for (int h = 0; h < 4; ++h) {
      wa[h] += W[lane * 64 + h * 16 + m] * av;
      wb[h] += W[(64 + lane) * 64 + h * 16 + m] * av;
    }
  }
  int w  = (bid * 256 + tid) >> 6;
  int nw = (nblk * 256) >> 6;
  for (int n = w; n < N; n += nw) {
    float xa = x[(size_t)n * 128 + lane], xc = x[(size_t)n * 128 + 64 + lane];
    float4 r;
    r.x = xa * wa[0] + xc * wb[0]; r.y = xa * wa[1] + xc * wb[1];
    r.z = xa * wa[2] + xc * wb[2]; r.w = xa * wa[3] + xc * wb[3];
    #pragma unroll
    for (int m = 1; m < 64; m <<= 1) {
      r.x += __shfl_xor(r.x, m); r.y += __shfl_xor(r.y, m);
      r.z += __shfl_xor(r.z, m); r.w += __shfl_xor(r.w, m);
    }
    if (lane == 0) ((float4*)sdst)[n] = r;
  }
}

__global__ __launch_bounds__(256) void k_front(K1Args A) {
  int bid = blockIdx.x;
  if (bid < A.nbin) { bin_body(A, bid); return; }
  bid -= A.nbin;
  if (bid < B_CONV) { convert_body(A, bid); return; }
  bid -= B_CONV;
  if (bid < B_PACK) { pack_body(A.P, bid); return; }
  bid -= B_PACK;
  if (bid < B_SWH) { scores_body(A.xwh, A.P.W[4], A.P.a[4], A.sd_wh, NW, bid, B_SWH); return; }
  bid -= B_SWH;
  scores_body(A.xsup, A.P.W[5], A.P.a[5], A.sd_sup, NPS, bid, B_SSUP);
}

// ================= k_mid: fused CSR pass-B + node GEMMs (independent roles) =================
struct MidArgs {
  // csr
  const int* gCur; const uint32_t* binned; int* offs; int* ssorted;
  // gemm
  const bfu* xb; const bfu* Bp;
  bfu* hbAll; float* ssAll; float* sdAll; int nstrips;
};

// csr role, 256 threads: parallel bucket-base scan + 16-elem/thread hist scan
__device__ void csr_body(const MidArgs& M, int b) {
  __shared__ int hist[4096];
  __shared__ int wq[4];
  __shared__ int wsc[4];
  __shared__ int bbase_s, cnt_s;
  int tid = threadIdx.x;
  int lane = tid & 63, wid = tid >> 6;
  // bucket base/count via 256-wide scan over clamped cursors
  int cthis = (tid < NBUK) ? min(M.gCur[tid], BCAP) : 0;
  int incx = cthis;
  #pragma unroll
  for (int d = 1; d < 64; d <<= 1) { int t = __shfl_up(incx, d); if (lane >= d) incx += t; }
  if (lane == 63) wq[wid] = incx;
  #pragma unroll
  for (int k = 0; k < 16; ++k) hist[tid * 16 + k] = 0;
  __syncthreads();
  int wp = 0;
  for (int k = 0; k < wid; ++k) wp += wq[k];
  if (tid == b) { int inclusive = incx + wp; bbase_s = inclusive - cthis; cnt_s = cthis; }
  __syncthreads();
  int cnt = cnt_s, bbase = bbase_s;
  const uint32_t* bk = M.binned + (size_t)b * BCAP;
  for (int i = tid; i < cnt; i += 256)
    atomicAdd(&hist[bk[i] >> 17], 1);
  __syncthreads();
  // block exclusive scan over 4096 (16 slots/thread)
  int t16 = tid * 16;
  int v[16], tsum = 0;
  #pragma unroll
  for (int k = 0; k < 16; ++k) { v[k] = hist[t16 + k]; tsum += v[k]; }
  int inc = tsum;
  #pragma unroll
  for (int d = 1; d < 64; d <<= 1) { int t = __shfl_up(inc, d); if (lane >= d) inc += t; }
  if (lane == 63) wsc[wid] = inc;
  __syncthreads();
  int wpre = 0;
  for (int k = 0; k < wid; ++k) wpre += wsc[k];
  int run = inc - tsum + wpre;
  #pragma unroll
  for (int k = 0; k < 16; ++k) { hist[t16 + k] = run; run += v[k]; }
  __syncthreads();
  // coalesced offs write for this bucket's slot range
  int sbase, nslots;
  if (b < 98)        { sbase = b << 12;                nslots = min(4096, 4 * NS - sbase); }
  else if (b < 118)  { int lb = (b - 98) << 8;  sbase = 4 * NS + lb;      nslots = min(256, NW - lb); }
  else               { int lb = (b - 118) << 7; sbase = 4 * NS + NW + lb; nslots = min(128, NPS - lb); }
  for (int i = tid; i < nslots; i += 256) M.offs[sbase + i] = bbase + hist[i];
  if (b == NBUK - 1 && tid == 0) M.offs[NFLAT] = bbase + cnt;
  __syncthreads();
  // scatter (hist doubles as cursor)
  for (int i = tid; i < cnt; i += 256) {
    uint32_t vv = bk[i];
    int p = atomicAdd(&hist[vv >> 17], 1);
    M.ssorted[bbase + p] = (int)(vv & 0x1FFFFu);
  }
}

// gemm role (REVERTED to measured-good r4 form): B-frags preloaded once per wave,
// latency-tolerant compute loop. Per-kq reload variant measured 140us (r7) vs ~80us.
__device__ void gemm_body(const MidArgs& G, int bloc) {
  int p = bloc >> 9;        // 0..2 : type pair (2p, 2p+1)
  int bsub = bloc & 511;
  const bfu* Bp0 = G.Bp + (size_t)(2 * p) * 10240;
  const bfu* Bp1 = G.Bp + (size_t)(2 * p + 1) * 10240;
  bfu* hb0 = G.hbAll + (size_t)(2 * p) * NS * 64;
  bfu* hb1 = G.hbAll + (size_t)(2 * p + 1) * NS * 64;
  float* ss0 = G.ssAll + (size_t)(2 * p) * NS * 4;
  float* ss1 = G.ssAll + (size_t)(2 * p + 1) * NS * 4;
  float* sd0 = G.sdAll + (size_t)(2 * p) * NS * 4;
  float* sd1 = G.sdAll + (size_t)(2 * p + 1) * NS * 4;
  int lane = threadIdx.x & 63;
  int l15 = lane & 15, q = lane >> 4;
  int w  = (int)((bsub * 256 + threadIdx.x) >> 6);
  int nw = (512 * 256) >> 6;
  s8v bfr[10][4];
  #pragma unroll
  for (int nt = 0; nt < 5; ++nt)
    #pragma unroll
    for (int kq = 0; kq < 4; ++kq) {
      bfr[nt][kq]     = *(const s8v*)(Bp0 + (size_t)(nt * 16 + l15) * 128 + kq * 32 + q * 8);
      bfr[5 + nt][kq] = *(const s8v*)(Bp1 + (size_t)(nt * 16 + l15) * 128 + kq * 32 + q * 8);
    }
  for (int s = w; s < G.nstrips; s += nw) {
    int mb = s * 16;
    f4v acc[10];
    #pragma unroll
    for (int u = 0; u < 10; ++u) acc[u] = (f4v){0.f, 0.f, 0.f, 0.f};
    const bfu* ar = G.xb + (size_t)(mb + l15) * 128 + q * 8;
    #pragma unroll
    for (int kq = 0; kq < 4; ++kq) {
      s8v af = *(const s8v*)(ar + kq * 32);
      #pragma unroll
      for (int u = 0; u < 10; ++u)
        acc[u] = __builtin_amdgcn_mfma_f32_16x16x32_bf16(af, bfr[u][kq], acc[u], 0, 0, 0);
    }
    #pragma unroll
    for (int u = 0; u < 10; ++u) {
      int nt = (u < 5) ? u : u - 5;
      bfu* hb = (u < 5) ? hb0 : hb1;
      float* ssrc = (u < 5) ? ss0 : ss1;
      float* sdst = (u < 5) ? sd0 : sd1;
      int c = nt * 16 + l15;
      #pragma unroll
      for (int r = 0; r < 4; ++r) {
        int node = mb + q * 4 + r;
        float v = acc[u][r];
        if (c < 64)      hb[(size_t)node * 64 + c] = f2bf(v);
        else if (c < 68) ssrc[(size_t)node * 4 + (c - 64)] = v;
        else if (c < 72) sdst[(size_t)node * 4 + (c - 68)] = v;
      }
    }
  }
}

__global__ __launch_bounds__(256, 2) void k_mid(MidArgs M) {
  int bid = blockIdx.x;
  if (bid < NBUK) { csr_body(M, bid); return; }
  gemm_body(M, bid - NBUK);
}

// ================= fused softmax-aggregate (v3 math, 2048-block persistent grid) =================
struct AggArgs {
  const int* offs; const int* srcs;
  const bfu* hbAll;     // [6][NS][64]
  const float* ssAll;   // [6][NS][4]
  const float* sdAll;   // [6][NS][4] (types 4,5 unused)
  const float* sd_wh; const float* sd_sup;
  bfu* osku; bfu* owh; bfu* osup;
};

__global__ __launch_bounds__(256) void k_megaagg(AggArgs A) {
  int lane = threadIdx.x & 63;
  int q = lane >> 4, m = lane & 15, h = m >> 2;
  int hh = m & 3;          // head this lane SCORES
  int i0 = m >> 2;         // edge slot (0..3) this lane scores
  int qsh = q << 4;
  int sl0 = qsh + h;       // base of wgt-broadcast source lane: + 4*(i&3)
  int w  = (int)((blockIdx.x * 256 + threadIdx.x) >> 6);
  int nw = (int)((gridDim.x * 256) >> 6);
  for (int n = w; n < NS + NW + NPS; n += nw) {
    if (n < NS) {
      const int* ob = A.offs + (size_t)n * 4;
      int4 o = *(const int4*)ob;
      int o4 = ob[4];
      int sb = (q == 0) ? o.x : (q == 1) ? o.y : (q == 2) ? o.z : o.w;
      int se = (q == 0) ? o.y : (q == 1) ? o.z : (q == 2) ? o.w : o4;
      int len = se - sb;
      int maxlen = max(max(o.y - o.x, o.z - o.y), max(o.w - o.z, o4 - o.w));
      float sdq = A.sdAll[((size_t)q * NS + n) * 4 + hh];
      uint32_t tbase = (uint32_t)q * (uint32_t)NS;
      float den = 0.f, a0 = 0.f, a1 = 0.f, a2 = 0.f, a3 = 0.f;
      for (int j0 = 0; j0 < maxlen; j0 += 16) {
        int ei = j0 + m;
        int sidx = (ei < len) ? A.srcs[sb + ei] : 0;
        int gmax = min(16, maxlen - j0);
        for (int jj = 0; jj < gmax; jj += 8) {
          // phase 1: score edges (jj+i0) and (jj+4+i0) for head hh
          int sA = __shfl(sidx, qsh + jj + i0);
          int sB = __shfl(sidx, qsh + jj + 4 + i0);
          float scA = A.ssAll[(tbase + (uint32_t)sA) * 4u + (uint32_t)hh];
          float scB = A.ssAll[(tbase + (uint32_t)sB) * 4u + (uint32_t)hh];
          float eA = scA + sdq, eB = scB + sdq;
          eA = eA > 0.f ? eA : (__expf(eA) - 1.f);
          eB = eB > 0.f ? eB : (__expf(eB) - 1.f);
          float wA = (j0 + jj + i0)     < len ? __expf(eA) : 0.f;
          float wB = (j0 + jj + 4 + i0) < len ? __expf(eB) : 0.f;
          // phase 2: gather h-rows + broadcast weights
          uint2 hv[8]; float wg[8];
          #pragma unroll
          for (int i = 0; i < 8; ++i) {
            int s = __shfl(sidx, qsh + jj + i);
            uint32_t nb = tbase + (uint32_t)s;
            hv[i] = *(const uint2*)(A.hbAll + nb * 64u + (uint32_t)(m * 4));
            wg[i] = __shfl((i & 4) ? wB : wA, sl0 + ((i & 3) << 2));
          }
          #pragma unroll
          for (int i = 0; i < 8; ++i) {
            float wgt = wg[i];
            den += wgt;
            a0 = fmaf(__uint_as_float(hv[i].x << 16), wgt, a0);
            a1 = fmaf(__uint_as_float(hv[i].x & 0xffff0000u), wgt, a1);
            a2 = fmaf(__uint_as_float(hv[i].y << 16), wgt, a2);
            a3 = fmaf(__uint_as_float(hv[i].y & 0xffff0000u), wgt, a3);
          }
        }
      }
      float inv = __builtin_amdgcn_rcpf(den + 1e-12f);
      float r0 = a0 * inv, r1 = a1 * inv, r2 = a2 * inv, r3 = a3 * inv;
      r0 += __shfl_xor(r0, 16); r0 += __shfl_xor(r0, 32);
      r1 += __shfl_xor(r1, 16); r1 += __shfl_xor(r1, 32);
      r2 += __shfl_xor(r2, 16); r2 += __shfl_xor(r2, 32);
      r3 += __shfl_xor(r3, 16); r3 += __shfl_xor(r3, 32);
      if (q == 0) {
        uint2 pk;
        pk.x = (uint32_t)f2bf(r0) | ((uint32_t)f2bf(r1) << 16);
        pk.y = (uint32_t)f2bf(r2) | ((uint32_t)f2bf(r3) << 16);
        *(uint2*)(A.osku + (size_t)n * 64 + m * 4) = pk;
      }
    } else {
      int tt, nl; const float* sd; bfu* op;
      int fi;
      if (n < NS + NW) { tt = 4; nl = n - NS; fi = 4 * NS + nl; sd = A.sd_wh; op = A.owh + (size_t)nl * 64; }
      else { tt = 5; nl = n - NS - NW; fi = 4 * NS + NW + nl; sd = A.sd_sup; op = A.osup + (size_t)nl * 64; }
      int beg = A.offs[fi], end = A.offs[fi + 1];
      uint32_t tbase = (uint32_t)tt * (uint32_t)NS;
      float sdq = sd[(size_t)nl * 4 + hh];
      float den = 0.f, a0 = 0.f, a1 = 0.f, a2 = 0.f, a3 = 0.f;
      for (int cb = beg; cb < end; cb += 64) {
        int rem = min(64, end - cb);
        int sidx = (lane < rem) ? A.srcs[cb + lane] : 0;
        for (int jb = 0; jb < rem; jb += 32) {
          // phase 1: score edges jb+4*i0+q and jb+4*(i0+4)+q for head hh
          int eA = jb + 4 * i0 + q;
          int sA = __shfl(sidx, eA);
          int sB = __shfl(sidx, eA + 16);
          float scA = A.ssAll[(tbase + (uint32_t)sA) * 4u + (uint32_t)hh];
          float scB = A.ssAll[(tbase + (uint32_t)sB) * 4u + (uint32_t)hh];
          float fA = scA + sdq, fB = scB + sdq;
          fA = fA > 0.f ? fA : (__expf(fA) - 1.f);
          fB = fB > 0.f ? fB : (__expf(fB) - 1.f);
          float wA = (eA)      < rem ? __expf(fA) : 0.f;
          float wB = (eA + 16) < rem ? __expf(fB) : 0.f;
          uint2 hv[8]; float wg[8];
          #pragma unroll
          for (int i = 0; i < 8; ++i) {
            int s = __shfl(sidx, jb + 4 * i + q);
            uint32_t nb = tbase + (uint32_t)s;
            hv[i] = *(const uint2*)(A.hbAll + nb * 64u + (uint32_t)(m * 4));
            wg[i] = __shfl((i & 4) ? wB : wA, sl0 + ((i & 3) << 2));
          }
          #pragma unroll
          for (int i = 0; i < 8; ++i) {
            float wgt = wg[i];
            den += wgt;
            a0 = fmaf(__uint_as_float(hv[i].x << 16), wgt, a0);
            a1 = fmaf(__uint_as_float(hv[i].x & 0xffff0000u), wgt, a1);
            a2 = fmaf(__uint_as_float(hv[i].y << 16), wgt, a2);
            a3 = fmaf(__uint_as_float(hv[i].y & 0xffff0000u), wgt, a3);
          }
        }
      }
      den += __shfl_xor(den, 16); den += __shfl_xor(den, 32);
      a0 += __shfl_xor(a0, 16); a0 += __shfl_xor(a0, 32);
      a1 += __shfl_xor(a1, 16); a1 += __shfl_xor(a1, 32);
      a2 += __shfl_xor(a2, 16); a2 += __shfl_xor(a2, 32);
      a3 += __shfl_xor(a3, 16); a3 += __shfl_xor(a3, 32);
      float inv = __builtin_amdgcn_rcpf(den + 1e-12f);
      if (q == 0) {
        uint2 pk;
        pk.x = (uint32_t)f2bf(a0 * inv) | ((uint32_t)f2bf(a1 * inv) << 16);
        pk.y = (uint32_t)f2bf(a2 * inv) | ((uint32_t)f2bf(a3 * inv) << 16);
        *(uint2*)(op + m * 4) = pk;
      }
    }
  }
}

// ================= MFMA finish: all 3 node sets in ONE dispatch (4 strips/wave) =================
struct FinArgs {
  const bfu* agg0; const bfu* agg1; const bfu* agg2;
  const bfu* x0; const bfu* x1; const bfu* x2;
  float* out0; float* out1; float* out2;
  const bfu* Pp; const bfu* Rp;
  const float* pb; const float* g; const float* bb;
  int bcut0, bcut1;   // role boundaries: [0,bcut0)=sku, [bcut0,bcut1)=wh, rest=sup
};

__global__ __launch_bounds__(256) void k_finish(FinArgs F) {
  int bid = blockIdx.x;
  int role = (bid >= F.bcut0) + (bid >= F.bcut1);
  int b0 = (role == 0) ? 0 : (role == 1) ? F.bcut0 : F.bcut1;
  int nb = (role == 0) ? F.bcut0 : (role == 1) ? (F.bcut1 - F.bcut0) : ((int)gridDim.x - F.bcut1);
  int bloc = bid - b0;
  const bfu* aggb = (role == 0) ? F.agg0 : (role == 1) ? F.agg1 : F.agg2;
  const bfu* xbf  = (role == 0) ? F.x0 : (role == 1) ? F.x1 : F.x2;
  float* outp     = (role == 0) ? F.out0 : (role == 1) ? F.out1 : F.out2;
  int koff    = (role == 0) ? 0 : 64;
  int N       = (role == 0) ? NS : (role == 1) ? NW : NPS;
  int nstrips = (role == 0) ? NSTRIPS : (role == 1) ? (NWPAD / 16) : (NPS / 16);

  int lane = threadIdx.x & 63, l15 = lane & 15, q = lane >> 4;
  int w  = (int)((bloc * 256 + threadIdx.x) >> 6);
  int nw = nb << 2;
  s8v bP[4][2], bR[4][4];
  float pbv[4], gv[4], bv[4];
  #pragma unroll
  for (int c = 0; c < 4; ++c) {
    const bfu* pr = F.Pp + (size_t)(c * 16 + l15) * 128 + koff;
    bP[c][0] = *(const s8v*)(pr + q * 8);
    bP[c][1] = *(const s8v*)(pr + 32 + q * 8);
    const bfu* rr = F.Rp + (size_t)(c * 16 + l15) * 128;
    #pragma unroll
    for (int kq = 0; kq < 4; ++kq) bR[c][kq] = *(const s8v*)(rr + kq * 32 + q * 8);
    pbv[c] = F.pb[c * 16 + l15]; gv[c] = F.g[c * 16 + l15]; bv[c] = F.bb[c * 16 + l15];
  }
  for (int s = w; s < nstrips; s += nw) {
    int mb = s * 16;
    const bfu* ar = aggb + (size_t)(mb + l15) * 64 + q * 8;
    const bfu* xr = xbf + (size_t)(mb + l15) * 128 + q * 8;
    s8v a0 = *(const s8v*)ar, a1 = *(const s8v*)(ar + 32);
    s8v x0 = *(const s8v*)xr, x1 = *(const s8v*)(xr + 32),
        x2 = *(const s8v*)(xr + 64), x3 = *(const s8v*)(xr + 96);
    f4v acc[4];
    #pragma unroll
    for (int c = 0; c < 4; ++c) {
      acc[c] = (f4v){0.f, 0.f, 0.f, 0.f};
      acc[c] = __builtin_amdgcn_mfma_f32_16x16x32_bf16(a0, bP[c][0], acc[c], 0, 0, 0);
      acc[c] = __builtin_amdgcn_mfma_f32_16x16x32_bf16(a1, bP[c][1], acc[c], 0, 0, 0);
      acc[c] = __builtin_amdgcn_mfma_f32_16x16x32_bf16(x0, bR[c][0], acc[c], 0, 0, 0);
      acc[c] = __builtin_amdgcn_mfma_f32_16x16x32_bf16(x1, bR[c][1], acc[c], 0, 0, 0);
      acc[c] = __builtin_amdgcn_mfma_f32_16x16x32_bf16(x2, bR[c][2], acc[c], 0, 0, 0);
      acc[c] = __builtin_amdgcn_mfma_f32_16x16x32_bf16(x3, bR[c][3], acc[c], 0, 0, 0);
    }
    #pragma unroll
    for (int r = 0; r < 4; ++r) {
      int row = mb + q * 4 + r;
      float y0 = acc[0][r] + pbv[0], y1 = acc[1][r] + pbv[1];
      float y2 = acc[2][r] + pbv[2], y3 = acc[3][r] + pbv[3];
      float s1 = y0 + y1 + y2 + y3;
      s1 += __shfl_xor(s1, 1); s1 += __shfl_xor(s1, 2);
      s1 += __shfl_xor(s1, 4); s1 += __shfl_xor(s1, 8);
      float mu = s1 * 0.015625f;
      float d0 = y0 - mu, d1 = y1 - mu, d2 = y2 - mu, d3 = y3 - mu;
      float s2 = d0 * d0 + d1 * d1 + d2 * d2 + d3 * d3;
      s2 += __shfl_xor(s2, 1); s2 += __shfl_xor(s2, 2);
      s2 += __shfl_xor(s2, 4); s2 += __shfl_xor(s2, 8);
      float rs = rsqrtf(s2 * 0.015625f + 1e-5f);
      if (row < N) {
        float* orow = outp + (size_t)row * 64 + l15;
        orow[0]  = d0 * rs * gv[0] + bv[0];
        orow[16] = d1 * rs * gv[1] + bv[1];
        orow[32] = d2 * rs * gv[2] + bv[2];
        orow[48] = d3 * rs * gv[3] + bv[3];
      }
    }
  }
}

// ================= launch =================
extern "C" void kernel_launch(void* const* d_in, const int* in_sizes, int n_in,
                              void* d_out, int out_size, void* d_ws, size_t ws_size,
                              hipStream_t stream) {
  const float* x_sku = (const float*)d_in[0];
  const float* x_wh  = (const float*)d_in[1];
  const float* x_sup = (const float*)d_in[2];
  const float* Wt[6]; const float* at[6];
  for (int t = 0; t < 6; ++t) { Wt[t] = (const float*)d_in[3 + 2 * t]; at[t] = (const float*)d_in[4 + 2 * t]; }
  const float* projW = (const float*)d_in[15];
  const float* projb = (const float*)d_in[16];
  const float* lng   = (const float*)d_in[17];
  const float* lnb   = (const float*)d_in[18];
  const float* resW  = (const float*)d_in[19];
  const int* ei[6]; int Et[6];
  for (int t = 0; t < 6; ++t) { ei[t] = (const int*)d_in[20 + t]; Et[t] = in_sizes[20 + t] / 2; }
  float* out = (float*)d_out;

  int ETOT = 0;
  for (int t = 0; t < 6; ++t) ETOT += Et[t];

  char* ws = (char*)d_ws;
  size_t off = 0;
  auto alloc = [&](size_t bytes) { off = (off + 255) & ~(size_t)255; void* p = ws + off; off += bytes; return p; };

  bfu*  xb      = (bfu*)alloc((size_t)NS * DI * 2);
  bfu*  xb_wh   = (bfu*)alloc((size_t)NWPAD * DI * 2);
  bfu*  xb_sup  = (bfu*)alloc((size_t)NPS * DI * 2);
  bfu*  Bp      = (bfu*)alloc((size_t)6 * 80 * 128 * 2);
  bfu*  Rp      = (bfu*)alloc((size_t)64 * 128 * 2);
  bfu*  Pp      = (bfu*)alloc((size_t)64 * 128 * 2);
  bfu*  hbAll   = (bfu*)alloc((size_t)6 * NS * 64 * 2);
  float* ssAll  = (float*)alloc((size_t)6 * NS * 4 * 4);
  float* sdAll  = (float*)alloc((size_t)6 * NS * 4 * 4);
  float* sdst_wh  = (float*)alloc((size_t)NW * 4 * 4);
  float* sdst_sup = (float*)alloc((size_t)NPS * 4 * 4);
  // union: binned (used only before megaagg) aliases agg buffers (written by megaagg)
  size_t agg_bytes = ((size_t)NS + NWPAD + NPS) * 64 * 2;   // 13.7 MB
  size_t bin_bytes = (size_t)NBUK * BCAP * 4;               // 11.0 MB
  char* un = (char*)alloc(agg_bytes > bin_bytes ? agg_bytes : bin_bytes);
  bfu* agg_sku = (bfu*)un;
  bfu* agg_wh  = agg_sku + (size_t)NS * 64;
  bfu* agg_sup = agg_wh + (size_t)NWPAD * 64;
  uint32_t* binned = (uint32_t*)un;
  int* gCur    = (int*)alloc(256 * 4);
  int* offsb   = (int*)alloc((size_t)(NFLAT + 1) * 4);
  int* ssorted = (int*)alloc((size_t)ETOT * 4);

  // zero relative bucket cursors
  hipMemsetAsync(gCur, 0, NBUK * 4, stream);

  // ---- K1: fused bin + convert + pack + scores ----
  K1Args K;
  K.S.Ecum[0] = 0;
  for (int t = 0; t < 6; ++t) { K.S.ei[t] = ei[t]; K.S.E[t] = Et[t]; K.S.Ecum[t + 1] = K.S.Ecum[t] + Et[t]; }
  K.gCur = gCur; K.binned = binned; K.ETOT = ETOT;
  K.nbin = (ETOT + CHUNK - 1) / CHUNK;
  K.x0 = x_sku; K.o0 = xb;     K.n0 = NS * 16;
  K.x1 = x_wh;  K.o1 = xb_wh;  K.n1 = NW * 16;
  K.x2 = x_sup; K.o2 = xb_sup; K.n2 = NPS * 16;
  for (int t = 0; t < 6; ++t) { K.P.W[t] = Wt[t]; K.P.a[t] = at[t]; }
  K.P.resW = resW; K.P.projW = projW; K.P.Bp = Bp; K.P.Rp = Rp; K.P.Pp = Pp;
  K.xwh = x_wh; K.xsup = x_sup; K.sd_wh = sdst_wh; K.sd_sup = sdst_sup;
  int gfront = K.nbin + B_CONV + B_PACK + B_SWH + B_SSUP;
  k_front<<<gfront, 256, 0, stream>>>(K);

  // ---- K2: fused CSR pass-B + node GEMMs ----
  MidArgs M;
  M.gCur = gCur; M.binned = binned; M.offs = offsb; M.ssorted = ssorted;
  M.xb = xb; M.Bp = Bp; M.hbAll = hbAll; M.ssAll = ssAll; M.sdAll = sdAll; M.nstrips = NSTRIPS;
  k_mid<<<NBUK + 1536, 256, 0, stream>>>(M);

  // ---- fused aggregate (persistent grid) ----
  AggArgs A;
  A.offs = offsb; A.srcs = ssorted;
  A.hbAll = hbAll; A.ssAll = ssAll; A.sdAll = sdAll;
  A.sd_wh = sdst_wh; A.sd_sup = sdst_sup;
  A.osku = agg_sku; A.owh = agg_wh; A.osup = agg_sup;
  k_megaagg<<<2048, 256, 0, stream>>>(A);

  // ---- MFMA finish (all 3 node sets, one dispatch; ~4 strips/wave) ----
  FinArgs F;
  F.agg0 = agg_sku; F.agg1 = agg_wh; F.agg2 = agg_sup;
  F.x0 = xb; F.x1 = xb_wh; F.x2 = xb_sup;
  F.out0 = out; F.out1 = out + (size_t)NS * 64; F.out2 = out + (size_t)(NS + NW) * 64;
  F.Pp = Pp; F.Rp = Rp; F.pb = projb; F.g = lng; F.bb = lnb;
  F.bcut0 = 391; F.bcut1 = 391 + 20;
  k_finish<<<391 + 20 + 8, 256, 0, stream>>>(F);
}